// Round 10
// baseline (417.965 us; speedup 1.0000x reference)
//
#include <hip/hip_runtime.h>
#include <hip/hip_fp16.h>

#define N_NODES 100000
#define N_EDGES 1600000
#define IN_SIZE 256
#define HID 64
#define HEADS 2
#define DMODEL 128   // HEADS*HID
#define OUT_SZ 16

// CSR build via bucketed counting sort (r2 geometry — measured best)
#define BSHIFT 9                       // 512 nodes per bucket
#define BNODES 512
#define NB 196                         // ceil(100000/512)
#define CAP 16384                      // bucket capacity (mean 8163, +90 sigma)
#define EPB 4096                       // edges per bin_kernel block

typedef _Float16 f16x4 __attribute__((ext_vector_type(4)));
typedef _Float16 f16x8 __attribute__((ext_vector_type(8)));
typedef float f32x4 __attribute__((ext_vector_type(4)));

// Edge pack: bits [0,17) = src (src < 131072), bits [17,26) = dst & 511.

// GEMM tile: 128 rows x 128 cols, 4 waves; As/Bs 128 x 72 fp16.
#define GEMM_SMEM (128 * 72 * 2 + 128 * 72 * 2)   // 36864 B

// ---------------------------------------------------------------------------
// Fused weight prep + counts zeroing (runs first; deletes memset dispatch).
// ---------------------------------------------------------------------------

__global__ __launch_bounds__(256) void wt_fused_kernel(const float* __restrict__ W1,
                                                       _Float16* __restrict__ Wt1,
                                                       const float* __restrict__ W2,
                                                       _Float16* __restrict__ Wt2,
                                                       int* __restrict__ counts) {
    int tid = threadIdx.x;
    if (blockIdx.x == 0 && tid < NB) counts[tid] = 0;
    int i = blockIdx.x * 256 + tid;
    if (i < 128 * IN_SIZE) {
        int nr = i / IN_SIZE;
        int k = i - nr * IN_SIZE;
        Wt1[i] = (_Float16)W1[(size_t)k * 128 + nr];
    } else {
        int j = i - 128 * IN_SIZE;
        if (j < 128 * DMODEL) {
            int nr = j / DMODEL;
            int k = j - nr * DMODEL;
            Wt2[j] = (_Float16)W2[(size_t)k * 128 + nr];
        }
    }
}

// ---------------------------------------------------------------------------
// Phase 1: bin edges by dst>>9.  u32-packed edges, LDS counting-sort before
// flush -> coalesced per-bucket runs.
// ---------------------------------------------------------------------------

__global__ __launch_bounds__(256) void bin_kernel(const int* __restrict__ src,
                                                  const int* __restrict__ dst,
                                                  int* __restrict__ counts,
                                                  uint32_t* __restrict__ bucketbuf, int e) {
    __shared__ int hist[NB];
    __shared__ int lbase[NB + 1];
    __shared__ int gbase[NB];
    __shared__ uint32_t sbuf[EPB];     // bucket-sorted packed edges (16 KB)
    __shared__ int lds[256];
    int tid = threadIdx.x;
    int start = blockIdx.x * EPB;
    for (int i = tid; i < NB; i += 256) hist[i] = 0;
    __syncthreads();
    int pr[16];        // (bucket<<16) | local rank
    uint32_t pv[16];   // packed edge
    #pragma unroll
    for (int i = 0; i < 16; i++) {
        int idx = start + i * 256 + tid;
        pr[i] = -1;
        if (idx < e) {
            int d = dst[idx];
            int s = src[idx];
            int b = d >> BSHIFT;
            int r = atomicAdd(&hist[b], 1);     // LDS atomic: local rank
            pr[i] = (b << 16) | r;
            pv[i] = ((uint32_t)(d & (BNODES - 1)) << 17) | (uint32_t)s;
        }
    }
    __syncthreads();
    int h = (tid < NB) ? hist[tid] : 0;
    lds[tid] = h;
    __syncthreads();
    for (int off = 1; off < 256; off <<= 1) {
        int x = 0;
        if (tid >= off) x = lds[tid - off];
        __syncthreads();
        lds[tid] += x;
        __syncthreads();
    }
    if (tid < NB) lbase[tid] = lds[tid] - h;
    if (tid == NB - 1) lbase[NB] = lds[tid];
    if (tid < NB) gbase[tid] = atomicAdd(&counts[tid], h);   // reserve chunk
    __syncthreads();
    #pragma unroll
    for (int i = 0; i < 16; i++) {
        int p = pr[i];
        if (p >= 0) sbuf[lbase[p >> 16] + (p & 0xffff)] = pv[i];
    }
    __syncthreads();
    int total = lbase[NB];
    for (int i = tid; i < total; i += 256) {
        int lo = 0, hi = NB - 1;
        while (lo < hi) {
            int mid = (lo + hi + 1) >> 1;
            if (lbase[mid] <= i) lo = mid; else hi = mid - 1;
        }
        int posg = gbase[lo] + (i - lbase[lo]);
        if (posg < CAP)
            bucketbuf[(size_t)lo * CAP + posg] = sbuf[i];
    }
}

// ---------------------------------------------------------------------------
// csr body (device fn; shares a dispatch with gemm1).
// ---------------------------------------------------------------------------

__device__ __forceinline__ void csr_body(char* smem, int b,
                                         const uint32_t* __restrict__ bucketbuf,
                                         const int* __restrict__ counts,
                                         int* __restrict__ deg,
                                         int* __restrict__ offs,
                                         int* __restrict__ ssrc, int n) {
    int* hist = (int*)smem;            // 512
    int* cursor = hist + BNODES;       // 512
    int* lds = cursor + BNODES;        // 256
    int tid = threadIdx.x;

    int t = (tid < NB) ? min(counts[tid], CAP) : 0;
    lds[tid] = t;
    __syncthreads();
    for (int off = 1; off < 256; off <<= 1) {
        int x = 0;
        if (tid >= off) x = lds[tid - off];
        __syncthreads();
        lds[tid] += x;
        __syncthreads();
    }
    int base = (b == 0) ? 0 : lds[b - 1];
    int cnt = min(counts[b], CAP);
    __syncthreads();

    int node0 = b << BSHIFT;
    const uint32_t* ebuf = bucketbuf + (size_t)b * CAP;

    hist[tid] = 0;
    hist[tid + 256] = 0;
    __syncthreads();
    for (int i = tid; i < cnt; i += 256)
        atomicAdd(&hist[ebuf[i] >> 17], 1);
    __syncthreads();

    int h0 = hist[2 * tid], h1 = hist[2 * tid + 1];
    lds[tid] = h0 + h1;
    __syncthreads();
    for (int off = 1; off < 256; off <<= 1) {
        int x = 0;
        if (tid >= off) x = lds[tid - off];
        __syncthreads();
        lds[tid] += x;
        __syncthreads();
    }
    int excl = lds[tid] - (h0 + h1);
    cursor[2 * tid] = excl;
    cursor[2 * tid + 1] = excl + h0;
    int g0 = node0 + 2 * tid, g1 = g0 + 1;
    if (g0 < n) { deg[g0] = h0; offs[g0] = base + excl; }
    if (g1 < n) { deg[g1] = h1; offs[g1] = base + excl + h0; }
    __syncthreads();

    for (int i = tid; i < cnt; i += 256) {
        uint32_t ed = ebuf[i];
        int p = atomicAdd(&cursor[ed >> 17], 1);   // LDS atomic
        ssrc[base + p] = (int)(ed & 0x1FFFF);      // src in CSR order
    }
}

// ---------------------------------------------------------------------------
// Fused MFMA GEMM + attention coefficients + fp16 pack (device fn).
// NEW (r10): 128-row tile.  Per kt each wave does 32 MFMA against 20
// ds_read_b128 (was 16 vs 18): B-fragment loaded once, used by both
// row-groups; B-staging and barriers amortized over 2x rows.
// ---------------------------------------------------------------------------

template <int K, bool F16IN>
__device__ __forceinline__ void gemm_attn_body(char* smem, int bx,
                                               const void* __restrict__ Ap,
                                               const _Float16* __restrict__ Wt,
                                               const float* __restrict__ al,
                                               const float* __restrict__ ar,
                                               uint32_t* __restrict__ h16,
                                               float* __restrict__ el,
                                               float* __restrict__ er, int n) {
    _Float16* As = (_Float16*)smem;                     // 128 x 72
    _Float16* Bs = (_Float16*)(smem + 128 * 72 * 2);    // 128 x 72
    int tid = threadIdx.x;
    int w = tid >> 6;
    int lane = tid & 63;
    int c = lane & 15;
    int quad = lane >> 4;
    int r0 = bx * 128;

    f32x4 acc[2][8];
    #pragma unroll
    for (int rb = 0; rb < 2; rb++)
        #pragma unroll
        for (int t = 0; t < 8; t++) acc[rb][t] = (f32x4){0.f, 0.f, 0.f, 0.f};

    for (int kt = 0; kt < K; kt += 64) {
        // stage A tile (128 rows x 64 k)
        {
            int lr = tid >> 4;           // 0..15
            int lc = (tid & 15) * 4;     // 0..60 (halves)
            #pragma unroll
            for (int q = 0; q < 8; q++) {
                int row = lr + 16 * q;
                int gr = r0 + row;
                if constexpr (F16IN) {
                    const uint32_t* Af = (const uint32_t*)Ap;
                    uint2 v = make_uint2(0u, 0u);
                    if (gr < n) v = *(const uint2*)(Af + (size_t)gr * (K / 2) + (kt + lc) / 2);
                    *(uint2*)(As + row * 72 + lc) = v;
                } else {
                    const float* Af = (const float*)Ap;
                    float4 v = make_float4(0.f, 0.f, 0.f, 0.f);
                    if (gr < n) v = *(const float4*)(Af + (size_t)gr * K + kt + lc);
                    f16x4 hv = {(_Float16)v.x, (_Float16)v.y, (_Float16)v.z, (_Float16)v.w};
                    *(f16x4*)(As + row * 72 + lc) = hv;
                }
            }
            // stage Wt tile (128 n-rows x 64 k), fp16; 32 halves per thread
            int nr = tid >> 1;           // 0..127
            int kc = (tid & 1) * 32;     // 0 or 32
            const uint4* gsrc = (const uint4*)(Wt + (size_t)nr * K + kt + kc);
            uint4 v0 = gsrc[0];
            uint4 v1 = gsrc[1];
            uint4 v2 = gsrc[2];
            uint4 v3 = gsrc[3];
            *(uint4*)(Bs + nr * 72 + kc + 0)  = v0;
            *(uint4*)(Bs + nr * 72 + kc + 8)  = v1;
            *(uint4*)(Bs + nr * 72 + kc + 16) = v2;
            *(uint4*)(Bs + nr * 72 + kc + 24) = v3;
        }
        __syncthreads();

        #pragma unroll
        for (int kk = 0; kk < 64; kk += 32) {
            f16x8 a0 = *(const f16x8*)(As + (32 * w + c) * 72 + kk + quad * 8);
            f16x8 a1 = *(const f16x8*)(As + (32 * w + 16 + c) * 72 + kk + quad * 8);
            #pragma unroll
            for (int t = 0; t < 8; t++) {
                f16x8 b = *(const f16x8*)(Bs + (16 * t + c) * 72 + kk + quad * 8);
                acc[0][t] = __builtin_amdgcn_mfma_f32_16x16x32_f16(a0, b, acc[0][t], 0, 0, 0);
                acc[1][t] = __builtin_amdgcn_mfma_f32_16x16x32_f16(a1, b, acc[1][t], 0, 0, 0);
            }
        }
        __syncthreads();
    }

    // ---- epilogue: el/er (quad-wide reduction) + fp16 pack of h
    #pragma unroll
    for (int rb = 0; rb < 2; rb++) {
        #pragma unroll
        for (int i = 0; i < 4; i++) {
            int gr = r0 + 32 * w + 16 * rb + quad * 4 + i;
            float el0 = 0.f, el1 = 0.f, er0 = 0.f, er1 = 0.f;
            #pragma unroll
            for (int t = 0; t < 8; t++) {
                float hv = acc[rb][t][i];
                float alv = al[16 * t + c];
                float arv = ar[16 * t + c];
                if (t < 4) { el0 += hv * alv; er0 += hv * arv; }
                else       { el1 += hv * alv; er1 += hv * arv; }
            }
            #pragma unroll
            for (int off = 1; off < 16; off <<= 1) {
                el0 += __shfl_xor(el0, off);
                el1 += __shfl_xor(el1, off);
                er0 += __shfl_xor(er0, off);
                er1 += __shfl_xor(er1, off);
            }
            if (c == 0 && gr < n) {
                *(float2*)(el + 2 * gr) = make_float2(el0, el1);
                *(float2*)(er + 2 * gr) = make_float2(er0, er1);
            }
            #pragma unroll
            for (int t = 0; t < 8; t++) {
                float own = acc[rb][t][i];
                float other = __shfl_xor(own, 1);
                if ((c & 1) == 0 && gr < n) {
                    __half2 hh = __floats2half2_rn(own, other);
                    h16[(size_t)gr * 64 + 8 * t + (c >> 1)] = *(const uint32_t*)&hh;
                }
            }
        }
    }
}

// ---------------------------------------------------------------------------
// Merged dispatch: blocks [0,NB) run csr; blocks [NB, NB+gemmBlocks) run
// layer-1 GEMM (independent work; csr hides under gemm1).
// ---------------------------------------------------------------------------

__global__ __launch_bounds__(256) void csr_gemm1_kernel(const uint32_t* __restrict__ bucketbuf,
                                                        const int* __restrict__ counts,
                                                        int* __restrict__ deg,
                                                        int* __restrict__ offs,
                                                        int* __restrict__ ssrc,
                                                        const float* __restrict__ features,
                                                        const _Float16* __restrict__ Wt1,
                                                        const float* __restrict__ al,
                                                        const float* __restrict__ ar,
                                                        uint32_t* __restrict__ h16,
                                                        float* __restrict__ el,
                                                        float* __restrict__ er, int n) {
    __shared__ __align__(16) char smem[GEMM_SMEM];
    if (blockIdx.x < NB)
        csr_body(smem, blockIdx.x, bucketbuf, counts, deg, offs, ssrc, n);
    else
        gemm_attn_body<IN_SIZE, false>(smem, blockIdx.x - NB, features, Wt1,
                                       al, ar, h16, el, er, n);
}

__global__ __launch_bounds__(256) void gemm_attn2_kernel(const void* __restrict__ Ap,
                                                         const _Float16* __restrict__ Wt,
                                                         const float* __restrict__ al,
                                                         const float* __restrict__ ar,
                                                         uint32_t* __restrict__ h16,
                                                         float* __restrict__ el,
                                                         float* __restrict__ er, int n) {
    __shared__ __align__(16) char smem[GEMM_SMEM];
    gemm_attn_body<DMODEL, true>(smem, blockIdx.x, Ap, Wt, al, ar, h16, el, er, n);
}

// ---------------------------------------------------------------------------
// Per-node weighted aggregation — EXACT r7/r9 structure (best measured).
// ---------------------------------------------------------------------------

__device__ __forceinline__ float edge_w(float2 e, float erh, int head) {
    float x = (head ? e.y : e.x) + erh;
    x = x >= 0.f ? x : 0.2f * x;
    return __expf(x);
}

__device__ __forceinline__ void acc8(uint4 u, float w, float* a) {
    union { uint4 u4; f16x8 h8; } cv;
    cv.u4 = u;
    #pragma unroll
    for (int i = 0; i < 8; i++)
        a[i] = fmaf((float)cv.h8[i], w, a[i]);   // f16 src + f32 fma -> v_fma_mix_f32
}

__global__ __launch_bounds__(256) void agg_kernel(const uint32_t* __restrict__ hb,
                                                  const int* __restrict__ ssrc,
                                                  const float* __restrict__ el,
                                                  const float* __restrict__ er,
                                                  const float* __restrict__ bias,
                                                  const int* __restrict__ offs,
                                                  const int* __restrict__ deg,
                                                  uint32_t* __restrict__ out16, int n) {
    int wid = (blockIdx.x * blockDim.x + threadIdx.x) >> 6;
    int lane = threadIdx.x & 63;
    if (wid >= n) return;
    int start = offs[wid];
    int d = deg[wid];
    int g = lane >> 4;                 // edge-slot group (0..3)
    int fl = lane & 15;                // feature lane: feats 8fl..8fl+7
    int head = fl >> 3;                // feats 0..63 head0, 64..127 head1

    float2 erv = *(const float2*)(er + 2 * wid);
    float erh = head ? erv.y : erv.x;

    const int* sp = ssrc + start;
    const float2* el2 = (const float2*)el;
    const char* hbb = (const char*)hb;
    uint32_t foff = (uint32_t)(fl << 4);

    float a[8];
    #pragma unroll
    for (int i = 0; i < 8; i++) a[i] = 0.f;
    float psum = 0.f;

    int j = 0;
    if (d >= 16) {
        int s0 = sp[g];
        int s1 = sp[4 + g];
        int s2 = sp[8 + g];
        int s3 = sp[12 + g];
        for (; j + 32 <= d; j += 16) {
            // issue gathers for current indices
            float2 e0 = el2[s0];
            uint4 u0 = *(const uint4*)(hbb + (((uint32_t)s0 << 8) + foff));
            float2 e1 = el2[s1];
            uint4 u1 = *(const uint4*)(hbb + (((uint32_t)s1 << 8) + foff));
            float2 e2 = el2[s2];
            uint4 u2 = *(const uint4*)(hbb + (((uint32_t)s2 << 8) + foff));
            float2 e3 = el2[s3];
            uint4 u3 = *(const uint4*)(hbb + (((uint32_t)s3 << 8) + foff));
            // preload next iteration's indices (overlaps gather latency)
            int ns0 = sp[j + 16 + g];
            int ns1 = sp[j + 20 + g];
            int ns2 = sp[j + 24 + g];
            int ns3 = sp[j + 28 + g];
            float w0 = edge_w(e0, erh, head);
            float w1 = edge_w(e1, erh, head);
            float w2 = edge_w(e2, erh, head);
            float w3 = edge_w(e3, erh, head);
            psum += (w0 + w1) + (w2 + w3);
            acc8(u0, w0, a);
            acc8(u1, w1, a);
            acc8(u2, w2, a);
            acc8(u3, w3, a);
            s0 = ns0; s1 = ns1; s2 = ns2; s3 = ns3;
        }
        {   // final full 16-edge block (indices already in registers)
            float2 e0 = el2[s0];
            uint4 u0 = *(const uint4*)(hbb + (((uint32_t)s0 << 8) + foff));
            float2 e1 = el2[s1];
            uint4 u1 = *(const uint4*)(hbb + (((uint32_t)s1 << 8) + foff));
            float2 e2 = el2[s2];
            uint4 u2 = *(const uint4*)(hbb + (((uint32_t)s2 << 8) + foff));
            float2 e3 = el2[s3];
            uint4 u3 = *(const uint4*)(hbb + (((uint32_t)s3 << 8) + foff));
            float w0 = edge_w(e0, erh, head);
            float w1 = edge_w(e1, erh, head);
            float w2 = edge_w(e2, erh, head);
            float w3 = edge_w(e3, erh, head);
            psum += (w0 + w1) + (w2 + w3);
            acc8(u0, w0, a);
            acc8(u1, w1, a);
            acc8(u2, w2, a);
            acc8(u3, w3, a);
            j += 16;
        }
    }
    if (j < d) {                       // masked tail, up to 15 edges
        int last = d - 1;
        int i0 = j + g, i1 = j + 4 + g, i2 = j + 8 + g, i3 = j + 12 + g;
        int s0 = sp[min(i0, last)];
        int s1 = sp[min(i1, last)];
        int s2 = sp[min(i2, last)];
        int s3 = sp[min(i3, last)];
        float2 e0 = el2[s0];
        uint4 u0 = *(const uint4*)(hbb + (((uint32_t)s0 << 8) + foff));
        float2 e1 = el2[s1];
        uint4 u1 = *(const uint4*)(hbb + (((uint32_t)s1 << 8) + foff));
        float2 e2 = el2[s2];
        uint4 u2 = *(const uint4*)(hbb + (((uint32_t)s2 << 8) + foff));
        float2 e3 = el2[s3];
        uint4 u3 = *(const uint4*)(hbb + (((uint32_t)s3 << 8) + foff));
        float w0 = (i0 <= last) ? edge_w(e0, erh, head) : 0.f;
        float w1 = (i1 <= last) ? edge_w(e1, erh, head) : 0.f;
        float w2 = (i2 <= last) ? edge_w(e2, erh, head) : 0.f;
        float w3 = (i3 <= last) ? edge_w(e3, erh, head) : 0.f;
        psum += (w0 + w1) + (w2 + w3);
        acc8(u0, w0, a);
        acc8(u1, w1, a);
        acc8(u2, w2, a);
        acc8(u3, w3, a);
    }

    // merge the four per-slot edge streams (xor 16/32 keeps fl fixed)
    #pragma unroll
    for (int i = 0; i < 8; i++) {
        a[i] += __shfl_xor(a[i], 16);
        a[i] += __shfl_xor(a[i], 32);
    }
    psum += __shfl_xor(psum, 16);
    psum += __shfl_xor(psum, 32);

    if (lane < 16) {
        float inv = 1.f / (psum + 1e-9f);
        float4 b0 = *(const float4*)(bias + 8 * lane);
        float4 b1 = *(const float4*)(bias + 8 * lane + 4);
        float o[8];
        o[0] = fmaf(a[0], inv, b0.x);
        o[1] = fmaf(a[1], inv, b0.y);
        o[2] = fmaf(a[2], inv, b0.z);
        o[3] = fmaf(a[3], inv, b0.w);
        o[4] = fmaf(a[4], inv, b1.x);
        o[5] = fmaf(a[5], inv, b1.y);
        o[6] = fmaf(a[6], inv, b1.z);
        o[7] = fmaf(a[7], inv, b1.w);
        #pragma unroll
        for (int i = 0; i < 8; i++)
            o[i] = o[i] > 0.f ? o[i] : (__expf(o[i]) - 1.f);   // ELU fused
        __half2 h01 = __floats2half2_rn(o[0], o[1]);
        __half2 h23 = __floats2half2_rn(o[2], o[3]);
        __half2 h45 = __floats2half2_rn(o[4], o[5]);
        __half2 h67 = __floats2half2_rn(o[6], o[7]);
        uint4 ov = make_uint4(*(const uint32_t*)&h01, *(const uint32_t*)&h23,
                              *(const uint32_t*)&h45, *(const uint32_t*)&h67);
        ((uint4*)(out16 + (size_t)wid * 64))[lane] = ov;
    }
}

// ---------------------------------------------------------------------------
// Final linear: out[n][16] = x[n][128](fp16) @ Wl[128][16] + bl.
// ---------------------------------------------------------------------------

__global__ __launch_bounds__(256) void final_kernel(const uint32_t* __restrict__ x16,
                                                    const float* __restrict__ Wl,
                                                    const float* __restrict__ bl,
                                                    float* __restrict__ out, int n) {
    __shared__ float Ws[DMODEL * OUT_SZ];
    __shared__ float bs[OUT_SZ];
    int tid = threadIdx.x;
    for (int i = tid; i < DMODEL * OUT_SZ / 4; i += 256)
        ((float4*)Ws)[i] = ((const float4*)Wl)[i];
    if (tid < OUT_SZ) bs[tid] = bl[tid];
    __syncthreads();
    int node = blockIdx.x * 16 + (tid >> 4);
    int c = tid & 15;
    if (node >= n) return;
    const uint4* xr = (const uint4*)(x16 + (size_t)node * 64);
    float acc = bs[c];
    #pragma unroll
    for (int kk = 0; kk < 16; kk++) {
        uint4 v = xr[kk];
        float2 f0 = __half22float2(*(const __half2*)&v.x);
        float2 f1 = __half22float2(*(const __half2*)&v.y);
        float2 f2 = __half22float2(*(const __half2*)&v.z);
        float2 f3 = __half22float2(*(const __half2*)&v.w);
        acc += f0.x * Ws[(8 * kk + 0) * OUT_SZ + c];
        acc += f0.y * Ws[(8 * kk + 1) * OUT_SZ + c];
        acc += f1.x * Ws[(8 * kk + 2) * OUT_SZ + c];
        acc += f1.y * Ws[(8 * kk + 3) * OUT_SZ + c];
        acc += f2.x * Ws[(8 * kk + 4) * OUT_SZ + c];
        acc += f2.y * Ws[(8 * kk + 5) * OUT_SZ + c];
        acc += f3.x * Ws[(8 * kk + 6) * OUT_SZ + c];
        acc += f3.y * Ws[(8 * kk + 7) * OUT_SZ + c];
    }
    out[(size_t)node * OUT_SZ + c] = acc;
}

// ---------------------------------------------------------------------------

extern "C" void kernel_launch(void* const* d_in, const int* in_sizes, int n_in,
                              void* d_out, int out_size, void* d_ws, size_t ws_size,
                              hipStream_t stream) {
    const float* features = (const float*)d_in[0];
    const int*   src      = (const int*)d_in[1];
    const int*   dst      = (const int*)d_in[2];
    const float* W1  = (const float*)d_in[3];
    const float* al1 = (const float*)d_in[4];
    const float* ar1 = (const float*)d_in[5];
    const float* b1  = (const float*)d_in[6];
    const float* W2  = (const float*)d_in[7];
    const float* al2 = (const float*)d_in[8];
    const float* ar2 = (const float*)d_in[9];
    const float* b2  = (const float*)d_in[10];
    const float* Wl  = (const float*)d_in[11];
    const float* bl  = (const float*)d_in[12];
    float* out = (float*)d_out;

    const int n = N_NODES, e = N_EDGES;

    // workspace carve-up (all chunks 256B-aligned)
    char* w = (char*)d_ws;
    uint32_t* h16 = (uint32_t*)w;       w += (size_t)n * 64 * 4;       // 25.6 MB
    uint32_t* x1  = (uint32_t*)w;       w += (size_t)n * 64 * 4;       // 25.6 MB
    uint32_t* x2  = (uint32_t*)w;       w += 26 * 1024 * 1024;         // 26 MB (aliases bucketbuf)
    float* el   = (float*)w;            w += (size_t)n * 2 * 4;        // 0.8 MB
    float* er   = (float*)w;            w += (size_t)n * 2 * 4;        // 0.8 MB
    int* deg    = (int*)w;              w += 400128;
    int* offs   = (int*)w;              w += 400128;
    int* ssrc   = (int*)w;              w += (size_t)e * 4;            // 6.4 MB
    int* counts = (int*)w;              w += 1024;
    _Float16* Wt1 = (_Float16*)w;       w += 128 * IN_SIZE * 2;        // 64 KB
    _Float16* Wt2 = (_Float16*)w;       w += 128 * DMODEL * 2;         // 32 KB
    // bucketbuf (u32, NB*CAP*4 = 12.85 MB) aliases x2: consumed by
    // csr_gemm1 before agg2 writes x2 (stream-ordered).
    uint32_t* bucketbuf = (uint32_t*)x2;

    const int binBlocks = (e + EPB - 1) / EPB;   // 391
    const int wtBlocks = (128 * IN_SIZE + 128 * DMODEL + 255) / 256;   // 192
    const int gemmBlocks = (n + 127) / 128;      // 782
    const int aggBlocks = (n + 3) / 4;           // 25000
    const int finalBlocks = (n + 15) / 16;       // 6250

    // ---- weight prep + counts zeroing
    wt_fused_kernel<<<wtBlocks, 256, 0, stream>>>(W1, Wt1, W2, Wt2, counts);

    // ---- bin, then merged {csr | gemm1} (independent work in one dispatch)
    bin_kernel<<<binBlocks, 256, 0, stream>>>(src, dst, counts, bucketbuf, e);
    csr_gemm1_kernel<<<NB + gemmBlocks, 256, 0, stream>>>(bucketbuf, counts, deg, offs, ssrc,
                                                          features, Wt1, al1, ar1,
                                                          h16, el, er, n);

    // ---- layer 1 aggregation
    agg_kernel<<<aggBlocks, 256, 0, stream>>>(h16, ssrc, el, er, b1, offs, deg, x1, n);

    // ---- layer 2
    gemm_attn2_kernel<<<gemmBlocks, 256, 0, stream>>>(x1, Wt2, al2, ar2, h16, el, er, n);
    agg_kernel<<<aggBlocks, 256, 0, stream>>>(h16, ssrc, el, er, b2, offs, deg, x2, n);

    // ---- final linear
    final_kernel<<<finalBlocks, 256, 0, stream>>>(x2, Wl, bl, out, n);

    (void)in_sizes; (void)n_in; (void)out_size; (void)ws_size;
}

// Round 12
// 389.173 us; speedup vs baseline: 1.0740x; 1.0740x over previous
//
#include <hip/hip_runtime.h>
#include <hip/hip_fp16.h>

#define N_NODES 100000
#define N_EDGES 1600000
#define IN_SIZE 256
#define HID 64
#define HEADS 2
#define DMODEL 128   // HEADS*HID
#define OUT_SZ 16

// CSR build via bucketed counting sort (r2 geometry — measured best)
#define BSHIFT 9                       // 512 nodes per bucket
#define BNODES 512
#define NB 196                         // ceil(100000/512)
#define CAP 16384                      // bucket capacity (mean 8163, +90 sigma)
#define EPB 4096                       // edges per bin_kernel block

typedef _Float16 f16x4 __attribute__((ext_vector_type(4)));
typedef _Float16 f16x8 __attribute__((ext_vector_type(8)));
typedef float f32x4 __attribute__((ext_vector_type(4)));

// Edge pack: bits [0,17) = src (src < 131072), bits [17,26) = dst & 511.

// GEMM tile: 64 rows x 128 cols (r9 config — measured best; 128-row r10
// tile regressed both GEMM dispatches).
#define GEMM_SMEM (64 * 72 * 2 + 128 * 72 * 2)   // 27648 B

// ---------------------------------------------------------------------------
// Fused weight prep + counts zeroing (runs first; deletes memset dispatch).
// ---------------------------------------------------------------------------

__global__ __launch_bounds__(256) void wt_fused_kernel(const float* __restrict__ W1,
                                                       _Float16* __restrict__ Wt1,
                                                       const float* __restrict__ W2,
                                                       _Float16* __restrict__ Wt2,
                                                       int* __restrict__ counts) {
    int tid = threadIdx.x;
    if (blockIdx.x == 0 && tid < NB) counts[tid] = 0;
    int i = blockIdx.x * 256 + tid;
    if (i < 128 * IN_SIZE) {
        int nr = i / IN_SIZE;
        int k = i - nr * IN_SIZE;
        Wt1[i] = (_Float16)W1[(size_t)k * 128 + nr];
    } else {
        int j = i - 128 * IN_SIZE;
        if (j < 128 * DMODEL) {
            int nr = j / DMODEL;
            int k = j - nr * DMODEL;
            Wt2[j] = (_Float16)W2[(size_t)k * 128 + nr];
        }
    }
}

// ---------------------------------------------------------------------------
// Phase 1: bin edges by dst>>9.  u32-packed edges, LDS counting-sort before
// flush.  NEW (r11): the flush's bucket lookup was an 8-step DEPENDENT LDS
// binary search per element (~120cy latency each step); now the scatter
// records each slot's bucket in sbkt[] (u16), so the flush is 2 independent
// LDS reads + 1 coalesced global write.
// ---------------------------------------------------------------------------

__global__ __launch_bounds__(256) void bin_kernel(const int* __restrict__ src,
                                                  const int* __restrict__ dst,
                                                  int* __restrict__ counts,
                                                  uint32_t* __restrict__ bucketbuf, int e) {
    __shared__ int hist[NB];
    __shared__ int lbase[NB + 1];
    __shared__ int gbase[NB];
    __shared__ uint32_t sbuf[EPB];           // bucket-sorted packed edges (16 KB)
    __shared__ unsigned short sbkt[EPB];     // bucket id per sorted slot (8 KB)
    __shared__ int lds[256];
    int tid = threadIdx.x;
    int start = blockIdx.x * EPB;
    for (int i = tid; i < NB; i += 256) hist[i] = 0;
    __syncthreads();
    int pr[16];        // (bucket<<16) | local rank
    uint32_t pv[16];   // packed edge
    #pragma unroll
    for (int i = 0; i < 16; i++) {
        int idx = start + i * 256 + tid;
        pr[i] = -1;
        if (idx < e) {
            int d = dst[idx];
            int s = src[idx];
            int b = d >> BSHIFT;
            int r = atomicAdd(&hist[b], 1);     // LDS atomic: local rank
            pr[i] = (b << 16) | r;
            pv[i] = ((uint32_t)(d & (BNODES - 1)) << 17) | (uint32_t)s;
        }
    }
    __syncthreads();
    int h = (tid < NB) ? hist[tid] : 0;
    lds[tid] = h;
    __syncthreads();
    for (int off = 1; off < 256; off <<= 1) {
        int x = 0;
        if (tid >= off) x = lds[tid - off];
        __syncthreads();
        lds[tid] += x;
        __syncthreads();
    }
    if (tid < NB) lbase[tid] = lds[tid] - h;
    if (tid == NB - 1) lbase[NB] = lds[tid];
    if (tid < NB) gbase[tid] = atomicAdd(&counts[tid], h);   // reserve chunk
    __syncthreads();
    #pragma unroll
    for (int i = 0; i < 16; i++) {
        int p = pr[i];
        if (p >= 0) {
            int b = p >> 16;
            int pos = lbase[b] + (p & 0xffff);
            sbuf[pos] = pv[i];
            sbkt[pos] = (unsigned short)b;
        }
    }
    __syncthreads();
    int total = lbase[NB];
    for (int i = tid; i < total; i += 256) {
        int b = sbkt[i];
        int posg = gbase[b] + (i - lbase[b]);
        if (posg < CAP)
            bucketbuf[(size_t)b * CAP + posg] = sbuf[i];
    }
}

// ---------------------------------------------------------------------------
// csr body (device fn; shares a dispatch with gemm1).
// ---------------------------------------------------------------------------

__device__ __forceinline__ void csr_body(char* smem, int b,
                                         const uint32_t* __restrict__ bucketbuf,
                                         const int* __restrict__ counts,
                                         int* __restrict__ deg,
                                         int* __restrict__ offs,
                                         int* __restrict__ ssrc, int n) {
    int* hist = (int*)smem;            // 512
    int* cursor = hist + BNODES;       // 512
    int* lds = cursor + BNODES;        // 256
    int tid = threadIdx.x;

    int t = (tid < NB) ? min(counts[tid], CAP) : 0;
    lds[tid] = t;
    __syncthreads();
    for (int off = 1; off < 256; off <<= 1) {
        int x = 0;
        if (tid >= off) x = lds[tid - off];
        __syncthreads();
        lds[tid] += x;
        __syncthreads();
    }
    int base = (b == 0) ? 0 : lds[b - 1];
    int cnt = min(counts[b], CAP);
    __syncthreads();

    int node0 = b << BSHIFT;
    const uint32_t* ebuf = bucketbuf + (size_t)b * CAP;

    hist[tid] = 0;
    hist[tid + 256] = 0;
    __syncthreads();
    for (int i = tid; i < cnt; i += 256)
        atomicAdd(&hist[ebuf[i] >> 17], 1);
    __syncthreads();

    int h0 = hist[2 * tid], h1 = hist[2 * tid + 1];
    lds[tid] = h0 + h1;
    __syncthreads();
    for (int off = 1; off < 256; off <<= 1) {
        int x = 0;
        if (tid >= off) x = lds[tid - off];
        __syncthreads();
        lds[tid] += x;
        __syncthreads();
    }
    int excl = lds[tid] - (h0 + h1);
    cursor[2 * tid] = excl;
    cursor[2 * tid + 1] = excl + h0;
    int g0 = node0 + 2 * tid, g1 = g0 + 1;
    if (g0 < n) { deg[g0] = h0; offs[g0] = base + excl; }
    if (g1 < n) { deg[g1] = h1; offs[g1] = base + excl + h0; }
    __syncthreads();

    for (int i = tid; i < cnt; i += 256) {
        uint32_t ed = ebuf[i];
        int p = atomicAdd(&cursor[ed >> 17], 1);   // LDS atomic
        ssrc[base + p] = (int)(ed & 0x1FFFF);      // src in CSR order
    }
}

// ---------------------------------------------------------------------------
// Fused MFMA GEMM + attention coefficients + fp16 pack (device fn).
// r9 64-row tile (measured best; r10's 128-row regressed).
// ---------------------------------------------------------------------------

template <int K, bool F16IN>
__device__ __forceinline__ void gemm_attn_body(char* smem, int bx,
                                               const void* __restrict__ Ap,
                                               const _Float16* __restrict__ Wt,
                                               const float* __restrict__ al,
                                               const float* __restrict__ ar,
                                               uint32_t* __restrict__ h16,
                                               float* __restrict__ el,
                                               float* __restrict__ er, int n) {
    _Float16* As = (_Float16*)smem;                    // 64 x 72
    _Float16* Bs = (_Float16*)(smem + 64 * 72 * 2);    // 128 x 72
    int tid = threadIdx.x;
    int w = tid >> 6;
    int lane = tid & 63;
    int c = lane & 15;
    int quad = lane >> 4;
    int r0 = bx * 64;

    f32x4 acc[8];
    #pragma unroll
    for (int t = 0; t < 8; t++) acc[t] = (f32x4){0.f, 0.f, 0.f, 0.f};

    for (int kt = 0; kt < K; kt += 64) {
        // stage A tile (64 rows x 64 k)
        {
            int lr = tid >> 4;           // 0..15
            int lc = (tid & 15) * 4;     // 0..60 (halves)
            #pragma unroll
            for (int q = 0; q < 4; q++) {
                int row = lr + 16 * q;
                int gr = r0 + row;
                if constexpr (F16IN) {
                    const uint32_t* Af = (const uint32_t*)Ap;
                    uint2 v = make_uint2(0u, 0u);
                    if (gr < n) v = *(const uint2*)(Af + (size_t)gr * (K / 2) + (kt + lc) / 2);
                    *(uint2*)(As + row * 72 + lc) = v;
                } else {
                    const float* Af = (const float*)Ap;
                    float4 v = make_float4(0.f, 0.f, 0.f, 0.f);
                    if (gr < n) v = *(const float4*)(Af + (size_t)gr * K + kt + lc);
                    f16x4 hv = {(_Float16)v.x, (_Float16)v.y, (_Float16)v.z, (_Float16)v.w};
                    *(f16x4*)(As + row * 72 + lc) = hv;
                }
            }
            // stage Wt tile (128 n-rows x 64 k), fp16; 32 halves per thread
            int nr = tid >> 1;           // 0..127
            int kc = (tid & 1) * 32;     // 0 or 32
            const uint4* gsrc = (const uint4*)(Wt + (size_t)nr * K + kt + kc);
            uint4 v0 = gsrc[0];
            uint4 v1 = gsrc[1];
            uint4 v2 = gsrc[2];
            uint4 v3 = gsrc[3];
            *(uint4*)(Bs + nr * 72 + kc + 0)  = v0;
            *(uint4*)(Bs + nr * 72 + kc + 8)  = v1;
            *(uint4*)(Bs + nr * 72 + kc + 16) = v2;
            *(uint4*)(Bs + nr * 72 + kc + 24) = v3;
        }
        __syncthreads();

        #pragma unroll
        for (int kk = 0; kk < 64; kk += 32) {
            f16x8 a = *(const f16x8*)(As + (16 * w + c) * 72 + kk + quad * 8);
            #pragma unroll
            for (int t = 0; t < 8; t++) {
                f16x8 b = *(const f16x8*)(Bs + (16 * t + c) * 72 + kk + quad * 8);
                acc[t] = __builtin_amdgcn_mfma_f32_16x16x32_f16(a, b, acc[t], 0, 0, 0);
            }
        }
        __syncthreads();
    }

    // ---- epilogue: el/er (quad-wide reduction) + fp16 pack of h
    #pragma unroll
    for (int i = 0; i < 4; i++) {
        int gr = r0 + 16 * w + quad * 4 + i;
        float el0 = 0.f, el1 = 0.f, er0 = 0.f, er1 = 0.f;
        #pragma unroll
        for (int t = 0; t < 8; t++) {
            float hv = acc[t][i];
            float alv = al[16 * t + c];
            float arv = ar[16 * t + c];
            if (t < 4) { el0 += hv * alv; er0 += hv * arv; }
            else       { el1 += hv * alv; er1 += hv * arv; }
        }
        #pragma unroll
        for (int off = 1; off < 16; off <<= 1) {
            el0 += __shfl_xor(el0, off);
            el1 += __shfl_xor(el1, off);
            er0 += __shfl_xor(er0, off);
            er1 += __shfl_xor(er1, off);
        }
        if (c == 0 && gr < n) {
            *(float2*)(el + 2 * gr) = make_float2(el0, el1);
            *(float2*)(er + 2 * gr) = make_float2(er0, er1);
        }
        #pragma unroll
        for (int t = 0; t < 8; t++) {
            float own = acc[t][i];
            float other = __shfl_xor(own, 1);
            if ((c & 1) == 0 && gr < n) {
                __half2 hh = __floats2half2_rn(own, other);
                h16[(size_t)gr * 64 + 8 * t + (c >> 1)] = *(const uint32_t*)&hh;
            }
        }
    }
}

// ---------------------------------------------------------------------------
// Merged dispatch: blocks [0,NB) run csr; blocks [NB, NB+gemmBlocks) run
// layer-1 GEMM (independent work; csr hides under gemm1).
// ---------------------------------------------------------------------------

__global__ __launch_bounds__(256) void csr_gemm1_kernel(const uint32_t* __restrict__ bucketbuf,
                                                        const int* __restrict__ counts,
                                                        int* __restrict__ deg,
                                                        int* __restrict__ offs,
                                                        int* __restrict__ ssrc,
                                                        const float* __restrict__ features,
                                                        const _Float16* __restrict__ Wt1,
                                                        const float* __restrict__ al,
                                                        const float* __restrict__ ar,
                                                        uint32_t* __restrict__ h16,
                                                        float* __restrict__ el,
                                                        float* __restrict__ er, int n) {
    __shared__ __align__(16) char smem[GEMM_SMEM];
    if (blockIdx.x < NB)
        csr_body(smem, blockIdx.x, bucketbuf, counts, deg, offs, ssrc, n);
    else
        gemm_attn_body<IN_SIZE, false>(smem, blockIdx.x - NB, features, Wt1,
                                       al, ar, h16, el, er, n);
}

__global__ __launch_bounds__(256) void gemm_attn2_kernel(const void* __restrict__ Ap,
                                                         const _Float16* __restrict__ Wt,
                                                         const float* __restrict__ al,
                                                         const float* __restrict__ ar,
                                                         uint32_t* __restrict__ h16,
                                                         float* __restrict__ el,
                                                         float* __restrict__ er, int n) {
    __shared__ __align__(16) char smem[GEMM_SMEM];
    gemm_attn_body<DMODEL, true>(smem, blockIdx.x, Ap, Wt, al, ar, h16, el, er, n);
}

// ---------------------------------------------------------------------------
// Per-node weighted aggregation — EXACT r7/r9 structure (best measured).
// ---------------------------------------------------------------------------

__device__ __forceinline__ float edge_w(float2 e, float erh, int head) {
    float x = (head ? e.y : e.x) + erh;
    x = x >= 0.f ? x : 0.2f * x;
    return __expf(x);
}

__device__ __forceinline__ void acc8(uint4 u, float w, float* a) {
    union { uint4 u4; f16x8 h8; } cv;
    cv.u4 = u;
    #pragma unroll
    for (int i = 0; i < 8; i++)
        a[i] = fmaf((float)cv.h8[i], w, a[i]);   // f16 src + f32 fma -> v_fma_mix_f32
}

__global__ __launch_bounds__(256) void agg_kernel(const uint32_t* __restrict__ hb,
                                                  const int* __restrict__ ssrc,
                                                  const float* __restrict__ el,
                                                  const float* __restrict__ er,
                                                  const float* __restrict__ bias,
                                                  const int* __restrict__ offs,
                                                  const int* __restrict__ deg,
                                                  uint32_t* __restrict__ out16, int n) {
    int wid = (blockIdx.x * blockDim.x + threadIdx.x) >> 6;
    int lane = threadIdx.x & 63;
    if (wid >= n) return;
    int start = offs[wid];
    int d = deg[wid];
    int g = lane >> 4;                 // edge-slot group (0..3)
    int fl = lane & 15;                // feature lane: feats 8fl..8fl+7
    int head = fl >> 3;                // feats 0..63 head0, 64..127 head1

    float2 erv = *(const float2*)(er + 2 * wid);
    float erh = head ? erv.y : erv.x;

    const int* sp = ssrc + start;
    const float2* el2 = (const float2*)el;
    const char* hbb = (const char*)hb;
    uint32_t foff = (uint32_t)(fl << 4);

    float a[8];
    #pragma unroll
    for (int i = 0; i < 8; i++) a[i] = 0.f;
    float psum = 0.f;

    int j = 0;
    if (d >= 16) {
        int s0 = sp[g];
        int s1 = sp[4 + g];
        int s2 = sp[8 + g];
        int s3 = sp[12 + g];
        for (; j + 32 <= d; j += 16) {
            // issue gathers for current indices
            float2 e0 = el2[s0];
            uint4 u0 = *(const uint4*)(hbb + (((uint32_t)s0 << 8) + foff));
            float2 e1 = el2[s1];
            uint4 u1 = *(const uint4*)(hbb + (((uint32_t)s1 << 8) + foff));
            float2 e2 = el2[s2];
            uint4 u2 = *(const uint4*)(hbb + (((uint32_t)s2 << 8) + foff));
            float2 e3 = el2[s3];
            uint4 u3 = *(const uint4*)(hbb + (((uint32_t)s3 << 8) + foff));
            // preload next iteration's indices (overlaps gather latency)
            int ns0 = sp[j + 16 + g];
            int ns1 = sp[j + 20 + g];
            int ns2 = sp[j + 24 + g];
            int ns3 = sp[j + 28 + g];
            float w0 = edge_w(e0, erh, head);
            float w1 = edge_w(e1, erh, head);
            float w2 = edge_w(e2, erh, head);
            float w3 = edge_w(e3, erh, head);
            psum += (w0 + w1) + (w2 + w3);
            acc8(u0, w0, a);
            acc8(u1, w1, a);
            acc8(u2, w2, a);
            acc8(u3, w3, a);
            s0 = ns0; s1 = ns1; s2 = ns2; s3 = ns3;
        }
        {   // final full 16-edge block (indices already in registers)
            float2 e0 = el2[s0];
            uint4 u0 = *(const uint4*)(hbb + (((uint32_t)s0 << 8) + foff));
            float2 e1 = el2[s1];
            uint4 u1 = *(const uint4*)(hbb + (((uint32_t)s1 << 8) + foff));
            float2 e2 = el2[s2];
            uint4 u2 = *(const uint4*)(hbb + (((uint32_t)s2 << 8) + foff));
            float2 e3 = el2[s3];
            uint4 u3 = *(const uint4*)(hbb + (((uint32_t)s3 << 8) + foff));
            float w0 = edge_w(e0, erh, head);
            float w1 = edge_w(e1, erh, head);
            float w2 = edge_w(e2, erh, head);
            float w3 = edge_w(e3, erh, head);
            psum += (w0 + w1) + (w2 + w3);
            acc8(u0, w0, a);
            acc8(u1, w1, a);
            acc8(u2, w2, a);
            acc8(u3, w3, a);
            j += 16;
        }
    }
    if (j < d) {                       // masked tail, up to 15 edges
        int last = d - 1;
        int i0 = j + g, i1 = j + 4 + g, i2 = j + 8 + g, i3 = j + 12 + g;
        int s0 = sp[min(i0, last)];
        int s1 = sp[min(i1, last)];
        int s2 = sp[min(i2, last)];
        int s3 = sp[min(i3, last)];
        float2 e0 = el2[s0];
        uint4 u0 = *(const uint4*)(hbb + (((uint32_t)s0 << 8) + foff));
        float2 e1 = el2[s1];
        uint4 u1 = *(const uint4*)(hbb + (((uint32_t)s1 << 8) + foff));
        float2 e2 = el2[s2];
        uint4 u2 = *(const uint4*)(hbb + (((uint32_t)s2 << 8) + foff));
        float2 e3 = el2[s3];
        uint4 u3 = *(const uint4*)(hbb + (((uint32_t)s3 << 8) + foff));
        float w0 = (i0 <= last) ? edge_w(e0, erh, head) : 0.f;
        float w1 = (i1 <= last) ? edge_w(e1, erh, head) : 0.f;
        float w2 = (i2 <= last) ? edge_w(e2, erh, head) : 0.f;
        float w3 = (i3 <= last) ? edge_w(e3, erh, head) : 0.f;
        psum += (w0 + w1) + (w2 + w3);
        acc8(u0, w0, a);
        acc8(u1, w1, a);
        acc8(u2, w2, a);
        acc8(u3, w3, a);
    }

    // merge the four per-slot edge streams (xor 16/32 keeps fl fixed)
    #pragma unroll
    for (int i = 0; i < 8; i++) {
        a[i] += __shfl_xor(a[i], 16);
        a[i] += __shfl_xor(a[i], 32);
    }
    psum += __shfl_xor(psum, 16);
    psum += __shfl_xor(psum, 32);

    if (lane < 16) {
        float inv = 1.f / (psum + 1e-9f);
        float4 b0 = *(const float4*)(bias + 8 * lane);
        float4 b1 = *(const float4*)(bias + 8 * lane + 4);
        float o[8];
        o[0] = fmaf(a[0], inv, b0.x);
        o[1] = fmaf(a[1], inv, b0.y);
        o[2] = fmaf(a[2], inv, b0.z);
        o[3] = fmaf(a[3], inv, b0.w);
        o[4] = fmaf(a[4], inv, b1.x);
        o[5] = fmaf(a[5], inv, b1.y);
        o[6] = fmaf(a[6], inv, b1.z);
        o[7] = fmaf(a[7], inv, b1.w);
        #pragma unroll
        for (int i = 0; i < 8; i++)
            o[i] = o[i] > 0.f ? o[i] : (__expf(o[i]) - 1.f);   // ELU fused
        __half2 h01 = __floats2half2_rn(o[0], o[1]);
        __half2 h23 = __floats2half2_rn(o[2], o[3]);
        __half2 h45 = __floats2half2_rn(o[4], o[5]);
        __half2 h67 = __floats2half2_rn(o[6], o[7]);
        uint4 ov = make_uint4(*(const uint32_t*)&h01, *(const uint32_t*)&h23,
                              *(const uint32_t*)&h45, *(const uint32_t*)&h67);
        ((uint4*)(out16 + (size_t)wid * 64))[lane] = ov;
    }
}

// ---------------------------------------------------------------------------
// Final linear: out[n][16] = x[n][128](fp16) @ Wl[128][16] + bl.
// ---------------------------------------------------------------------------

__global__ __launch_bounds__(256) void final_kernel(const uint32_t* __restrict__ x16,
                                                    const float* __restrict__ Wl,
                                                    const float* __restrict__ bl,
                                                    float* __restrict__ out, int n) {
    __shared__ float Ws[DMODEL * OUT_SZ];
    __shared__ float bs[OUT_SZ];
    int tid = threadIdx.x;
    for (int i = tid; i < DMODEL * OUT_SZ / 4; i += 256)
        ((float4*)Ws)[i] = ((const float4*)Wl)[i];
    if (tid < OUT_SZ) bs[tid] = bl[tid];
    __syncthreads();
    int node = blockIdx.x * 16 + (tid >> 4);
    int c = tid & 15;
    if (node >= n) return;
    const uint4* xr = (const uint4*)(x16 + (size_t)node * 64);
    float acc = bs[c];
    #pragma unroll
    for (int kk = 0; kk < 16; kk++) {
        uint4 v = xr[kk];
        float2 f0 = __half22float2(*(const __half2*)&v.x);
        float2 f1 = __half22float2(*(const __half2*)&v.y);
        float2 f2 = __half22float2(*(const __half2*)&v.z);
        float2 f3 = __half22float2(*(const __half2*)&v.w);
        acc += f0.x * Ws[(8 * kk + 0) * OUT_SZ + c];
        acc += f0.y * Ws[(8 * kk + 1) * OUT_SZ + c];
        acc += f1.x * Ws[(8 * kk + 2) * OUT_SZ + c];
        acc += f1.y * Ws[(8 * kk + 3) * OUT_SZ + c];
        acc += f2.x * Ws[(8 * kk + 4) * OUT_SZ + c];
        acc += f2.y * Ws[(8 * kk + 5) * OUT_SZ + c];
        acc += f3.x * Ws[(8 * kk + 6) * OUT_SZ + c];
        acc += f3.y * Ws[(8 * kk + 7) * OUT_SZ + c];
    }
    out[(size_t)node * OUT_SZ + c] = acc;
}

// ---------------------------------------------------------------------------

extern "C" void kernel_launch(void* const* d_in, const int* in_sizes, int n_in,
                              void* d_out, int out_size, void* d_ws, size_t ws_size,
                              hipStream_t stream) {
    const float* features = (const float*)d_in[0];
    const int*   src      = (const int*)d_in[1];
    const int*   dst      = (const int*)d_in[2];
    const float* W1  = (const float*)d_in[3];
    const float* al1 = (const float*)d_in[4];
    const float* ar1 = (const float*)d_in[5];
    const float* b1  = (const float*)d_in[6];
    const float* W2  = (const float*)d_in[7];
    const float* al2 = (const float*)d_in[8];
    const float* ar2 = (const float*)d_in[9];
    const float* b2  = (const float*)d_in[10];
    const float* Wl  = (const float*)d_in[11];
    const float* bl  = (const float*)d_in[12];
    float* out = (float*)d_out;

    const int n = N_NODES, e = N_EDGES;

    // workspace carve-up (all chunks 256B-aligned)
    char* w = (char*)d_ws;
    uint32_t* h16 = (uint32_t*)w;       w += (size_t)n * 64 * 4;       // 25.6 MB
    uint32_t* x1  = (uint32_t*)w;       w += (size_t)n * 64 * 4;       // 25.6 MB
    uint32_t* x2  = (uint32_t*)w;       w += 26 * 1024 * 1024;         // 26 MB (aliases bucketbuf)
    float* el   = (float*)w;            w += (size_t)n * 2 * 4;        // 0.8 MB
    float* er   = (float*)w;            w += (size_t)n * 2 * 4;        // 0.8 MB
    int* deg    = (int*)w;              w += 400128;
    int* offs   = (int*)w;              w += 400128;
    int* ssrc   = (int*)w;              w += (size_t)e * 4;            // 6.4 MB
    int* counts = (int*)w;              w += 1024;
    _Float16* Wt1 = (_Float16*)w;       w += 128 * IN_SIZE * 2;        // 64 KB
    _Float16* Wt2 = (_Float16*)w;       w += 128 * DMODEL * 2;         // 32 KB
    // bucketbuf (u32, NB*CAP*4 = 12.85 MB) aliases x2: consumed by
    // csr_gemm1 before agg2 writes x2 (stream-ordered).
    uint32_t* bucketbuf = (uint32_t*)x2;

    const int binBlocks = (e + EPB - 1) / EPB;   // 391
    const int wtBlocks = (128 * IN_SIZE + 128 * DMODEL + 255) / 256;   // 192
    const int gemmBlocks = (n + 63) / 64;        // 1563
    const int aggBlocks = (n + 3) / 4;           // 25000
    const int finalBlocks = (n + 15) / 16;       // 6250

    // ---- weight prep + counts zeroing
    wt_fused_kernel<<<wtBlocks, 256, 0, stream>>>(W1, Wt1, W2, Wt2, counts);

    // ---- bin, then merged {csr | gemm1} (independent work in one dispatch)
    bin_kernel<<<binBlocks, 256, 0, stream>>>(src, dst, counts, bucketbuf, e);
    csr_gemm1_kernel<<<NB + gemmBlocks, 256, 0, stream>>>(bucketbuf, counts, deg, offs, ssrc,
                                                          features, Wt1, al1, ar1,
                                                          h16, el, er, n);

    // ---- layer 1 aggregation
    agg_kernel<<<aggBlocks, 256, 0, stream>>>(h16, ssrc, el, er, b1, offs, deg, x1, n);

    // ---- layer 2
    gemm_attn2_kernel<<<gemmBlocks, 256, 0, stream>>>(x1, Wt2, al2, ar2, h16, el, er, n);
    agg_kernel<<<aggBlocks, 256, 0, stream>>>(h16, ssrc, el, er, b2, offs, deg, x2, n);

    // ---- final linear
    final_kernel<<<finalBlocks, 256, 0, stream>>>(x2, Wl, bl, out, n);

    (void)in_sizes; (void)n_in; (void)out_size; (void)ws_size;
}